// Round 8
// baseline (1082.356 us; speedup 1.0000x reference)
//
#include <hip/hip_runtime.h>
#include <math.h>

#define HIDDEN   4096
#define NEXP     64
#define NTOK     16384
#define KCHUNKS  8
#define KC       (HIDDEN / KCHUNKS)   // 512 k per chunk
#define NG       (HIDDEN / 4)         // 1024 4-k groups total
#define GPC      (KC / 4)             // 128 groups per chunk
#define TT       16                   // tokens per wave

// ---------- Kernel 0: interleave W into workspace: Wti[g][e][dk] = W[e][4g+dk] ----------
// Makes the per-group W read one contiguous 1KB line per wave in kernel 1.
__global__ void winter(const float* __restrict__ W, float* __restrict__ Wti) {
    const int gid = blockIdx.x * 256 + threadIdx.x;   // 65536 float4 moves
    const int e   = gid >> 10;                        // 0..63
    const int g   = gid & 1023;                       // 0..1023
    const float4 v = *(const float4*)&W[(size_t)e * HIDDEN + g * 4];  // coalesced read
    *(float4*)&Wti[(size_t)g * 256 + e * 4] = v;
}

// ---------------- Kernel 1: split-K fp32 GEMM -> partial logits ----------------
// grid (1024 token subtiles, 8 k-chunks), block = 64 (1 wave). 8192 waves = 8/SIMD,
// 32 waves/CU, NO LDS, NO barriers.
// lane = expert (exactly 64). Per 4-k group g:
//   W:  1 x global_load_dwordx4 of Wti[g][lane][0..3] — coalesced 1KB/wave,
//       L2-resident (1MB), vmcnt domain only.
//   x:  16 block-uniform float4 loads -> s_load_dwordx4 (imm offsets, no addr arith),
//       lgkmcnt domain only (no DS in this kernel — r7's fatal DS+SMEM mixing on
//       lgkmcnt forced full-drain waits every group).
//   FMA: 64 v_fmac_f32 (acc[t] += xs_k * w_lane) = 128 issue-cyc per group.
// Per (token,expert) fmaf chain: k ascending within chunk — same chain as all
// passing rounds (r0-r7, absmax 0.0).
__global__ __launch_bounds__(64, 8)
void gemm_partial(const float* __restrict__ x, const float* __restrict__ Wti,
                  float* __restrict__ part) {
    const int lane  = threadIdx.x;          // expert
    const int t0    = blockIdx.x * TT;      // token base
    const int kc    = blockIdx.y;           // k chunk 0..7
    const int gbase = kc * GPC;             // group base

    float acc[TT];
#pragma unroll
    for (int t = 0; t < TT; ++t) acc[t] = 0.f;

    const float* __restrict__ wp = Wti + (size_t)gbase * 256 + lane * 4;

#pragma unroll 1
    for (int g = 0; g < GPC; ++g) {         // k = kc*512 + 4g + dk, ascending
        const float4 wq = *(const float4*)(wp + (size_t)g * 256);     // vector pipe
#pragma unroll
        for (int t = 0; t < TT; ++t) {
            // block-uniform address -> scalar pipe (s_load_dwordx4, imm offset g*16)
            const float4 xs = *(const float4*)&x[(size_t)(t0 + t) * HIDDEN
                                                 + kc * KC + g * 4];
            float a = fmaf(xs.x, wq.x, acc[t]);
            a       = fmaf(xs.y, wq.y, a);
            a       = fmaf(xs.z, wq.z, a);
            acc[t]  = fmaf(xs.w, wq.w, a);
        }
    }

    // write partial logits: part[kc][t0+t][lane] — 256B coalesced per store
    float* dst = part + ((size_t)kc * NTOK + t0) * NEXP + lane;
#pragma unroll
    for (int t = 0; t < TT; ++t)
        dst[(size_t)t * NEXP] = acc[t];
}

// ---------------- Kernel 2: reduce partials + bias, softmax, top-2 ----------------
// Byte-identical to the round-0 version (passed, absmax 0.0).
__global__ __launch_bounds__(256)
void softmax_top2(const float* __restrict__ part, const float* __restrict__ bias,
                  float* __restrict__ out) {
    const int lane = threadIdx.x & 63;
    const int wid  = threadIdx.x >> 6;
    const int t    = blockIdx.x * 4 + wid;

    float l = bias[lane];
#pragma unroll
    for (int c = 0; c < KCHUNKS; ++c)
        l += part[((size_t)c * NTOK + t) * NEXP + lane];

    // wave max
    float m = l;
#pragma unroll
    for (int s = 32; s > 0; s >>= 1)
        m = fmaxf(m, __shfl_xor(m, s, 64));

    // softmax denominator (deterministic butterfly)
    float ssum = expf(l - m);
#pragma unroll
    for (int s = 32; s > 0; s >>= 1)
        ssum += __shfl_xor(ssum, s, 64);

    // top-1: max value, lower index wins ties
    float v1 = l; int i1 = lane;
#pragma unroll
    for (int s = 32; s > 0; s >>= 1) {
        float ov = __shfl_xor(v1, s, 64);
        int   oi = __shfl_xor(i1, s, 64);
        if (ov > v1 || (ov == v1 && oi < i1)) { v1 = ov; i1 = oi; }
    }
    // top-2: exclude i1
    float v2 = (lane == i1) ? -INFINITY : l;
    int   i2 = lane;
#pragma unroll
    for (int s = 32; s > 0; s >>= 1) {
        float ov = __shfl_xor(v2, s, 64);
        int   oi = __shfl_xor(i2, s, 64);
        if (ov > v2 || (ov == v2 && oi < i2)) { v2 = ov; i2 = oi; }
    }

    if (lane == 0) {
        const float inv = 1.0f / ssum;
        out[(size_t)t * 2 + 0] = inv;                    // exp(v1-m)=1 since v1==m
        out[(size_t)t * 2 + 1] = expf(v2 - m) * inv;
        out[(size_t)2 * NTOK + t * 2 + 0] = (float)i1;   // indices read back as float32
        out[(size_t)2 * NTOK + t * 2 + 1] = (float)i2;
    }
}

extern "C" void kernel_launch(void* const* d_in, const int* in_sizes, int n_in,
                              void* d_out, int out_size, void* d_ws, size_t ws_size,
                              hipStream_t stream) {
    const float* x  = (const float*)d_in[0];
    const float* W  = (const float*)d_in[1];
    const float* b  = (const float*)d_in[2];
    float* out  = (float*)d_out;
    float* part = (float*)d_ws;                                  // 32 MB partials
    float* Wti  = part + (size_t)KCHUNKS * NTOK * NEXP;          // +1 MB interleaved W

    winter<<<dim3(256), 256, 0, stream>>>(W, Wti);
    dim3 g1(NTOK / TT, KCHUNKS);  // 8192 one-wave blocks = 8/SIMD, no LDS
    gemm_partial<<<g1, 64, 0, stream>>>(x, Wti, part);
    softmax_top2<<<NTOK / 4, 256, 0, stream>>>(part, b, out);
}